// Round 4
// baseline (342.920 us; speedup 1.0000x reference)
//
#include <hip/hip_runtime.h>

#define DMODEL   2048
#define NTHREADS 256
#define NBLOCKS  2048   // persistent grid: 8192 rows / 2048 = 4 rows per block

typedef float f32x4 __attribute__((ext_vector_type(4)));   // native vector: OK for nontemporal builtins

// sin/cos of theta (radians) via hardware v_sin_f32/v_cos_f32 (args in
// revolutions; fract-reduce is exact w.r.t. periodicity). Matches the
// reference 4096-entry lerp LUT to ~3e-7; threshold is 2e-2.
__device__ __forceinline__ void fast_sincos(float theta, float& s, float& c) {
    const float INV_TWO_PI = 0.15915494309189535f;
    float r  = theta * INV_TWO_PI;
    float rr = r - floorf(r);                 // [0,1) revolutions
#if __has_builtin(__builtin_amdgcn_sinf) && __has_builtin(__builtin_amdgcn_cosf)
    s = __builtin_amdgcn_sinf(rr);
    c = __builtin_amdgcn_cosf(rr);
#else
    s = __sinf(rr * 6.283185307179586f);
    c = __cosf(rr * 6.283185307179586f);
#endif
}

__device__ __forceinline__ float fast_rcp(float x) {
#if __has_builtin(__builtin_amdgcn_rcpf)
    return __builtin_amdgcn_rcpf(x);
#else
    return 1.0f / x;
#endif
}

__global__ __launch_bounds__(NTHREADS)
void liquid_echo_kernel(const float* __restrict__ x_real,
                        const float* __restrict__ x_imag,
                        const float* __restrict__ tvec,
                        const float* __restrict__ memory_real,
                        const float* __restrict__ memory_imag,
                        const float* __restrict__ w_trigger,
                        const float* __restrict__ b_trigger,
                        const float* __restrict__ w_state,
                        const float* __restrict__ b_state,
                        const float* __restrict__ kptr,
                        float* __restrict__ out,
                        size_t imag_off, int nrows)
{
    __shared__ float red[NTHREADS / 64];

    const int tid = threadIdx.x;
    const int c0  = tid * 4;
    const int c1  = (DMODEL / 2) + tid * 4;

    // ---- Hoisted per-column params (identical for every row this block does)
    float4 wt0 = *(const float4*)(w_trigger + c0);
    float4 wt1 = *(const float4*)(w_trigger + c1);
    float4 bt0 = *(const float4*)(b_trigger + c0);
    float4 bt1 = *(const float4*)(b_trigger + c1);
    float4 ws0 = *(const float4*)(w_state + c0);
    float4 ws1 = *(const float4*)(w_state + c1);
    float4 bs0 = *(const float4*)(b_state + c0);
    float4 bs1 = *(const float4*)(b_state + c1);

    float iwt[8] = {fast_rcp(1.0f + fabsf(wt0.x)), fast_rcp(1.0f + fabsf(wt0.y)),
                    fast_rcp(1.0f + fabsf(wt0.z)), fast_rcp(1.0f + fabsf(wt0.w)),
                    fast_rcp(1.0f + fabsf(wt1.x)), fast_rcp(1.0f + fabsf(wt1.y)),
                    fast_rcp(1.0f + fabsf(wt1.z)), fast_rcp(1.0f + fabsf(wt1.w))};
    float btv[8] = {bt0.x, bt0.y, bt0.z, bt0.w, bt1.x, bt1.y, bt1.z, bt1.w};
    float iws[8] = {fast_rcp(1.0f + fabsf(ws0.x)), fast_rcp(1.0f + fabsf(ws0.y)),
                    fast_rcp(1.0f + fabsf(ws0.z)), fast_rcp(1.0f + fabsf(ws0.w)),
                    fast_rcp(1.0f + fabsf(ws1.x)), fast_rcp(1.0f + fabsf(ws1.y)),
                    fast_rcp(1.0f + fabsf(ws1.z)), fast_rcp(1.0f + fabsf(ws1.w))};
    float bsv[8] = {bs0.x, bs0.y, bs0.z, bs0.w, bs1.x, bs1.y, bs1.z, bs1.w};

    const float k_eff = fabsf(kptr[0]) + 0.1f;

    #pragma unroll 1
    for (int row = blockIdx.x; row < nrows; row += NBLOCKS) {
        const size_t rb = (size_t)row * DMODEL;
        const float t_phi = tvec[row] * 1.6180339887498948f;   // PHI

        // ---- Issue all global loads for this row up front
        float4 xr0 = *(const float4*)(x_real + rb + c0);
        float4 xr1 = *(const float4*)(x_real + rb + c1);
        float4 xi0 = *(const float4*)(x_imag + rb + c0);
        float4 xi1 = *(const float4*)(x_imag + rb + c1);
        float4 mr0 = *(const float4*)(memory_real + rb + c0);
        float4 mr1 = *(const float4*)(memory_real + rb + c1);
        float4 mi0 = *(const float4*)(memory_imag + rb + c0);
        float4 mi1 = *(const float4*)(memory_imag + rb + c1);

        float xrv[8] = {xr0.x, xr0.y, xr0.z, xr0.w, xr1.x, xr1.y, xr1.z, xr1.w};
        float xiv[8] = {xi0.x, xi0.y, xi0.z, xi0.w, xi1.x, xi1.y, xi1.z, xi1.w};

        // ---- Phase 1: angle-sum identity -> one sincos per element
        float sxy[8];
        float partial = 0.0f;
        #pragma unroll
        for (int j = 0; j < 8; ++j) {
            float base = btv[j] + t_phi;
            sxy[j]     = xrv[j] + xiv[j];
            float ths  = fmaf(sxy[j], iwt[j], base + base);   // th_r + th_i
            float s, c;
            fast_sincos(ths, s, c);
            partial = fmaf(c, xrv[j], partial);
            partial = fmaf(s, xiv[j], partial);
        }

        // ---- Row reduction (barrier A protects red[] reuse across rows)
        #pragma unroll
        for (int off = 32; off > 0; off >>= 1)
            partial += __shfl_down(partial, off, 64);
        __syncthreads();
        if ((tid & 63) == 0) red[tid >> 6] = partial;
        __syncthreads();

        float tot   = red[0] + red[1] + red[2] + red[3];
        float ic    = tot * (1.0f / 45.254833995939045f);     // / sqrt(2048)
        ic          = fminf(1.0f, fmaxf(-1.0f, ic));
        float x_inv = (1.0f - ic) * 0.5f;
        const float alpha = __expf(-k_eff * x_inv);
        const float oma   = 1.0f - alpha;

        float mrv[8] = {mr0.x, mr0.y, mr0.z, mr0.w, mr1.x, mr1.y, mr1.z, mr1.w};
        float miv[8] = {mi0.x, mi0.y, mi0.z, mi0.w, mi1.x, mi1.y, mi1.z, mi1.w};

        // ---- Phase 2: blend + state phase, same identity
        float er[8], ei[8];
        #pragma unroll
        for (int j = 0; j < 8; ++j) {
            float sb  = fmaf(alpha, sxy[j], oma * (mrv[j] + miv[j]));
            float ths = fmaf(sb, iws[j], (bsv[j] + t_phi) * 2.0f);
            float s, c;
            fast_sincos(ths, s, c);
            er[j] = c;
            ei[j] = s;
        }

        // ---- Non-temporal stores: write-once stream, don't allocate in LLC
        float* outr = out + rb;
        float* outi = out + imag_off + rb;
        f32x4 vr0 = {er[0], er[1], er[2], er[3]};
        f32x4 vr1 = {er[4], er[5], er[6], er[7]};
        f32x4 vi0 = {ei[0], ei[1], ei[2], ei[3]};
        f32x4 vi1 = {ei[4], ei[5], ei[6], ei[7]};
        __builtin_nontemporal_store(vr0, (f32x4*)(outr + c0));
        __builtin_nontemporal_store(vr1, (f32x4*)(outr + c1));
        __builtin_nontemporal_store(vi0, (f32x4*)(outi + c0));
        __builtin_nontemporal_store(vi1, (f32x4*)(outi + c1));
    }
}

extern "C" void kernel_launch(void* const* d_in, const int* in_sizes, int n_in,
                              void* d_out, int out_size, void* d_ws, size_t ws_size,
                              hipStream_t stream) {
    const float* x_real      = (const float*)d_in[0];
    const float* x_imag      = (const float*)d_in[1];
    const float* t           = (const float*)d_in[2];
    const float* memory_real = (const float*)d_in[3];
    const float* memory_imag = (const float*)d_in[4];
    const float* w_trigger   = (const float*)d_in[5];
    const float* b_trigger   = (const float*)d_in[6];
    const float* w_state     = (const float*)d_in[7];
    const float* b_state     = (const float*)d_in[8];
    const float* k           = (const float*)d_in[9];
    // d_in[10..11] = sin/cos tables — superseded by HW trig
    float* out = (float*)d_out;

    int B = in_sizes[0] / DMODEL;
    size_t imag_off = (size_t)out_size / 2;
    int grid = (B < NBLOCKS) ? B : NBLOCKS;

    liquid_echo_kernel<<<grid, NTHREADS, 0, stream>>>(
        x_real, x_imag, t, memory_real, memory_imag,
        w_trigger, b_trigger, w_state, b_state, k,
        out, imag_off, B);
}